// Round 15
// baseline (141.726 us; speedup 1.0000x reference)
//
#include <hip/hip_runtime.h>
#include <cstdint>
#include <cstddef>

#define B_DIM  16
#define S_BANK 8192
#define S_REF  32
#define S_TOT  8224   // S_BANK + S_REF
#define NMERGE 32     // S_TOT - MAX_SLOTS
#define D      512
#define NCH    129    // ceil(S_TOT / 64)

typedef float vfloat4 __attribute__((ext_vector_type(4)));  // NT-store capable
typedef unsigned long long u64;
#define DEADPK 0xFFFFFFFFFFFFFFFFULL   // +inf sentinel in u64 ordering

// ---------------- bit helpers ------------------------------------------------
__device__ __forceinline__ int d_lo(double d){ union{double d; int i[2];}u; u.d=d; return u.i[0]; }
__device__ __forceinline__ int d_hi(double d){ union{double d; int i[2];}u; u.d=d; return u.i[1]; }
__device__ __forceinline__ double d_mk(int hi,int lo){ union{double d; int i[2];}u; u.i[0]=lo;u.i[1]=hi; return u.d; }
__device__ __forceinline__ int u_lo(u64 v){ return (int)(v & 0xFFFFFFFFULL); }
__device__ __forceinline__ int u_hi(u64 v){ return (int)(v >> 32); }
__device__ __forceinline__ u64 u_mk(int hi,int lo){ return ((u64)(unsigned)hi << 32) | (u64)(unsigned)lo; }
__device__ __forceinline__ u64 d_bits(double d){ union{double d; u64 u;}x; x.d=d; return x.u; }

// pack (positive f64 score, idx<16384) into one sortable u64 (low 14 mantissa
// bits replaced by idx => unsigned compare == lexicographic (score,idx)).
__device__ __forceinline__ u64 pack_score(double s, int j) {
    return (d_bits(s) & ~0x3FFFULL) | (u64)(unsigned)j;
}

// ---------------- DPP wave64 reductions / scans (VALU pipe) ------------------
template<int CTRL, int ROWM>
__device__ __forceinline__ u64 dpp_u64(u64 v) {
    int lo = __builtin_amdgcn_update_dpp(u_lo(v), u_lo(v), CTRL, ROWM, 0xF, false);
    int hi = __builtin_amdgcn_update_dpp(u_hi(v), u_hi(v), CTRL, ROWM, 0xF, false);
    return u_mk(hi, lo);
}
__device__ __forceinline__ u64 rl_u64(u64 v, int l) {
    int lo = __builtin_amdgcn_readlane(u_lo(v), l);
    int hi = __builtin_amdgcn_readlane(u_hi(v), l);
    return u_mk(hi, lo);
}
// reduction min over 64 lanes, broadcast
__device__ __forceinline__ u64 lexmin_wave_u64(u64 v) {
    u64 w;
    w = dpp_u64<0x111,0xF>(v); if (w < v) v = w;
    w = dpp_u64<0x112,0xF>(v); if (w < v) v = w;
    w = dpp_u64<0x114,0xF>(v); if (w < v) v = w;
    w = dpp_u64<0x118,0xF>(v); if (w < v) v = w;
    w = dpp_u64<0x142,0xF>(v); if (w < v) v = w;
    w = dpp_u64<0x143,0xF>(v); if (w < v) v = w;
    return rl_u64(v, 63);
}
// inclusive prefix-min scan (ascending lanes)
__device__ __forceinline__ u64 scan_min_incl(u64 v) {
    u64 w;
    w = dpp_u64<0x111,0xF>(v); if (w < v) v = w;   // row_shr:1
    w = dpp_u64<0x112,0xF>(v); if (w < v) v = w;
    w = dpp_u64<0x114,0xF>(v); if (w < v) v = w;
    w = dpp_u64<0x118,0xF>(v); if (w < v) v = w;
    w = dpp_u64<0x142,0xA>(v); if (w < v) v = w;   // bcast15 -> rows 1,3
    w = dpp_u64<0x143,0xC>(v); if (w < v) v = w;   // bcast31 -> rows 2,3
    return v;
}
// inclusive suffix-min scan (descending)
__device__ __forceinline__ u64 scan_min_suffix(u64 v, int lane) {
    u64 w;
    w = dpp_u64<0x101,0xF>(v); if (w < v) v = w;   // row_shl:1
    w = dpp_u64<0x102,0xF>(v); if (w < v) v = w;
    w = dpp_u64<0x104,0xF>(v); if (w < v) v = w;
    w = dpp_u64<0x108,0xF>(v); if (w < v) v = w;
    u64 t16 = rl_u64(v, 16), t32 = rl_u64(v, 32), t48 = rl_u64(v, 48);
    u64 s3 = t48;
    u64 s2 = (t32 < s3) ? t32 : s3;
    u64 s1 = (t16 < s2) ? t16 : s2;
    int row = lane >> 4;
    u64 add = (row == 0) ? s1 : (row == 1) ? s2 : (row == 2) ? s3 : DEADPK;
    if (add < v) v = add;
    return v;
}
template<int CTRL>
__device__ __forceinline__ void sum_level(double& v) {
    int lo2 = __builtin_amdgcn_update_dpp(0, d_lo(v), CTRL, 0xF, 0xF, true);
    int hi2 = __builtin_amdgcn_update_dpp(0, d_hi(v), CTRL, 0xF, 0xF, true);
    v += d_mk(hi2, lo2);
}
__device__ __forceinline__ double sum_wave(double v) {
    sum_level<0x111>(v); sum_level<0x112>(v); sum_level<0x114>(v);
    sum_level<0x118>(v); sum_level<0x142>(v); sum_level<0x143>(v);
    int lo = __builtin_amdgcn_readlane(d_lo(v), 63);
    int hi = __builtin_amdgcn_readlane(d_hi(v), 63);
    return d_mk(hi, lo);
}

__device__ __forceinline__ const float* slot_gptr(int id, int b,
        const float* bank, const float* refresh) {
    return (id < S_BANK) ? bank    + ((size_t)b * S_BANK + id) * D
                         : refresh + ((size_t)b * S_REF + (id - S_BANK)) * D;
}

// ---------------- Kernel 1: fused norms + chunk minima -----------------------
// One block per (batch, chunk). Per-slot arithmetic (lane layout, f64 add
// order, sum_wave, sqrt) textually identical to the old norms_kernel =>
// bit-identical values. Wave 3 additionally computes the chunk-boundary slot
// (base+64) locally so pair scores never cross blocks. Packed chunk min goes
// to c_pk_g; global packed min per batch via device-scope atomicMin (min over
// packed == lexmin == old argmin).
__global__ __launch_bounds__(256) void normchunk_kernel(const float* __restrict__ bank,
        const float* __restrict__ refresh, double* __restrict__ norms,
        u64* __restrict__ c_pk_g, u64* __restrict__ p0pk_g) {
    __shared__ double s_n[65];
    const int gb = B_DIM * NCH - 1 - (int)blockIdx.x;   // reverse order (as before)
    const int b = gb / NCH;
    const int c = gb - b * NCH;
    const int t = threadIdx.x, lane = t & 63, wid = t >> 6;
    const int base = c * 64;
    const int niter = (wid == 3) ? 17 : 16;             // wave 3: +boundary slot
    for (int i = 0; i < niter; ++i) {
        int s = base + wid * 16 + i;
        if (s >= S_TOT) break;
        const float4* src = (const float4*)(s < S_BANK
            ? bank    + ((size_t)b * S_BANK + s) * D
            : refresh + ((size_t)b * S_REF + (s - S_BANK)) * D);
        float4 f0 = src[lane];
        float4 f1 = src[lane + 64];
        double acc = 0.0;
        acc += (double)f0.x * f0.x + (double)f0.y * f0.y + (double)f0.z * f0.z + (double)f0.w * f0.w;
        acc += (double)f1.x * f1.x + (double)f1.y * f1.y + (double)f1.z * f1.z + (double)f1.w * f1.w;
        acc = sum_wave(acc);
        double nv = sqrt(acc);
        if (lane == 0) {
            s_n[s - base] = nv;
            if (i < 16) norms[b * S_TOT + s] = nv;      // boundary slot owned by neighbor
        }
    }
    __syncthreads();
    if (wid == 0) {
        int j = base + lane;
        u64 pk = DEADPK;
        if (j <= S_TOT - 2) pk = pack_score(s_n[lane] + s_n[lane + 1], j);
        pk = lexmin_wave_u64(pk);
        if (lane == 0) {
            c_pk_g[b * NCH + c] = pk;
            atomicMin(p0pk_g + b, pk);                  // device-scope
        }
    }
}

// ---------------- Kernel 2: fused walk + bulk gather -------------------------
#define NBULK (B_DIM * 4096)   // 65536 bulk blocks (2 output rows each)

__global__ __launch_bounds__(256) void fused_kernel(const float* __restrict__ bank,
        const float* __restrict__ refresh, const double* __restrict__ norms,
        const u64* __restrict__ c_pk_g, const u64* __restrict__ p0pk_g,
        int* __restrict__ flag_g, vfloat4* __restrict__ out) {
    // small LDS (walk role only; keeps bulk occupancy high)
    __shared__ double s_wimp[194];     // window imps, index g - wlo
    __shared__ u64    c_pk[NCH];
    __shared__ u64    pref[192], suf[192];
    __shared__ int    rec_L[NMERGE], rec_R[NMERGE];
    __shared__ u64    rec_chosen[NMERGE];
    __shared__ u64    s_PL, s_SR;
    __shared__ int    s_flag;

    const int t    = threadIdx.x;
    const int lane = t & 63;
    const int wid  = t >> 6;
    const double INF = __builtin_inf();

    if (blockIdx.x >= 16) {
        // ================= BULK GATHER BLOCK (no barrier, scalar p0) =========
        int e  = blockIdx.x - 16;
        int b  = e >> 12;                 // 4096 blocks per batch
        int pr = (e & 4095) << 1;         // rows pr, pr+1 (same batch)
        const int p0 = (int)(p0pk_g[b] & 0x3FFFULL);   // uniform scalar load
        int r = pr + (t >> 7);
        int c = t & 127;
        // rows outside the 32-row ambiguous zone [p0-31, p0] are walk-independent
        int s = -1;
        if (r < p0 - 31)      s = r;
        else if (r > p0)      s = r + 32;
        if (s >= 0) {
            const vfloat4* sp = (const vfloat4*)slot_gptr(s, b, bank, refresh);
            vfloat4 v = sp[c];
            __builtin_nontemporal_store(v, &out[((size_t)b * S_BANK + r) * (D / 4) + c]);
        }
        return;
    }

    // ================= WALK BLOCK (b = blockIdx.x) =================
    const int b = blockIdx.x;

    if (t < NCH) c_pk[t] = c_pk_g[b * NCH + t];   // for validation PL/SR
    const u64 pk_min0 = p0pk_g[b];
    const int p0 = (int)(pk_min0 & 0x3FFFULL);

    const int cmid = p0 >> 6;
    int wsx = cmid - 1;
    if (wsx < 0) wsx = 0;
    if (wsx > NCH - 3) wsx = NCH - 3;
    const int ws  = wsx;
    const int wlo = ws * 64;

    // stage ONLY the window imps (194 doubles)
    for (int j = t; j < 194; j += 256) {
        int g = wlo + j;
        if (g < S_TOT) s_wimp[j] = norms[b * S_TOT + g];
    }
    __syncthreads();

    float4 m0r, m1r;           // final merged vector (wave 0)

    if (wid == 0) {
        // ---- wave 0: cascade walk with register prefetch pipeline ----
        const float4* gA = (const float4*)slot_gptr(p0, b, bank, refresh);
        const float4* gB = (const float4*)slot_gptr(p0 + 1, b, bank, refresh);
        float4 a0 = gA[2 * lane], a1 = gA[2 * lane + 1];
        float4 b0 = gB[2 * lane], b1 = gB[2 * lane + 1];
        int q;
        q = (p0 - 1 >= 0) ? p0 - 1 : 0;
        const float4* gq = (const float4*)slot_gptr(q, b, bank, refresh);
        float4 cL0 = gq[2 * lane], cL1 = gq[2 * lane + 1];
        q = (p0 + 2 <= S_TOT - 1) ? p0 + 2 : S_TOT - 1;
        gq = (const float4*)slot_gptr(q, b, bank, refresh);
        float4 cR0 = gq[2 * lane], cR1 = gq[2 * lane + 1];
        q = (p0 - 2 >= 0) ? p0 - 2 : 0;
        gq = (const float4*)slot_gptr(q, b, bank, refresh);
        float4 fL0 = gq[2 * lane], fL1 = gq[2 * lane + 1];
        q = (p0 + 3 <= S_TOT - 1) ? p0 + 3 : S_TOT - 1;
        gq = (const float4*)slot_gptr(q, b, bank, refresh);
        float4 fR0 = gq[2 * lane], fR1 = gq[2 * lane + 1];

        m0r.x = 0.5f * (a0.x + b0.x); m0r.y = 0.5f * (a0.y + b0.y);
        m0r.z = 0.5f * (a0.z + b0.z); m0r.w = 0.5f * (a0.w + b0.w);
        m1r.x = 0.5f * (a1.x + b1.x); m1r.y = 0.5f * (a1.y + b1.y);
        m1r.z = 0.5f * (a1.z + b1.z); m1r.w = 0.5f * (a1.w + b1.w);
        double ss = 0.0;
        ss += (double)m0r.x * m0r.x + (double)m0r.y * m0r.y + (double)m0r.z * m0r.z + (double)m0r.w * m0r.w;
        ss += (double)m1r.x * m1r.x + (double)m1r.y * m1r.y + (double)m1r.z * m1r.z + (double)m1r.w * m1r.w;
        double nrm = sqrt(sum_wave(ss));
        int L = p0, R = p0 + 1;
        if (t == 0) { rec_L[0] = L; rec_R[0] = R; rec_chosen[0] = pk_min0; }

        for (int step = 1; step < NMERGE; ++step) {
            const int cl = L - 1, cr = R + 1;
            const bool hasL = (cl >= 0);
            const bool hasR = (cr < S_TOT);
            const double il = hasL ? s_wimp[cl - wlo] : INF;
            const double ir = hasR ? s_wimp[cr - wlo] : INF;
            const u64 pkL = hasL ? pack_score(il + nrm, cl) : DEADPK;
            const u64 pkR = hasR ? pack_score(nrm + ir, L)  : DEADPK;
            const bool goL = (pkL < pkR);
            const u64 chosen = goL ? pkL : pkR;
            float4 a0s, a1s, b0s, b1s;
            if (goL) { a0s = cL0; a1s = cL1; b0s = m0r; b1s = m1r; }
            else     { a0s = m0r; a1s = m1r; b0s = cR0; b1s = cR1; }
            m0r.x = 0.5f * (a0s.x + b0s.x); m0r.y = 0.5f * (a0s.y + b0s.y);
            m0r.z = 0.5f * (a0s.z + b0s.z); m0r.w = 0.5f * (a0s.w + b0s.w);
            m1r.x = 0.5f * (a1s.x + b1s.x); m1r.y = 0.5f * (a1s.y + b1s.y);
            m1r.z = 0.5f * (a1s.z + b1s.z); m1r.w = 0.5f * (a1s.w + b1s.w);
            if (goL) {
                L = cl;
                cL0 = fL0; cL1 = fL1;
                int nq = (L - 2 >= 0) ? L - 2 : 0;
                const float4* gp = (const float4*)slot_gptr(nq, b, bank, refresh);
                fL0 = gp[2 * lane]; fL1 = gp[2 * lane + 1];
            } else {
                R = cr;
                cR0 = fR0; cR1 = fR1;
                int nq = (R + 2 <= S_TOT - 1) ? R + 2 : S_TOT - 1;
                const float4* gp = (const float4*)slot_gptr(nq, b, bank, refresh);
                fR0 = gp[2 * lane]; fR1 = gp[2 * lane + 1];
            }
            double ss2 = 0.0;
            ss2 += (double)m0r.x * m0r.x + (double)m0r.y * m0r.y + (double)m0r.z * m0r.z + (double)m0r.w * m0r.w;
            ss2 += (double)m1r.x * m1r.x + (double)m1r.y * m1r.y + (double)m1r.z * m1r.z + (double)m1r.w * m1r.w;
            nrm = sqrt(sum_wave(ss2));
            if (t == 0) { rec_L[step] = L; rec_R[step] = R; rec_chosen[step] = chosen; }
        }
    } else {
        // ---- waves 1-3: validation precompute, CONCURRENT with walk ----
        int c = ws + (wid - 1);
        int idx = c * 64 + lane;
        u64 pk0 = (idx <= S_TOT - 2)
                    ? pack_score(s_wimp[idx - wlo] + s_wimp[idx + 1 - wlo], idx)
                    : DEADPK;
        pref[idx - wlo] = scan_min_incl(pk0);
        suf[idx - wlo]  = scan_min_suffix(pk0, lane);
        if (wid == 1) {
            u64 x0 = (lane < ws) ? c_pk[lane] : DEADPK;
            u64 x1 = (lane + 64 < ws) ? c_pk[lane + 64] : DEADPK;
            u64 pl = (x0 < x1) ? x0 : x1;
            pl = lexmin_wave_u64(pl);
            if (lane == 0) s_PL = pl;
        }
        if (wid == 2) {
            u64 y0 = (lane > ws + 2) ? c_pk[lane] : DEADPK;
            u64 y1 = (lane + 64 > ws + 2) ? c_pk[lane + 64] : DEADPK;
            u64 y2 = (lane == 0 && 128 > ws + 2) ? c_pk[128] : DEADPK;
            u64 sr = (y0 < y1) ? y0 : y1;
            sr = (sr < y2) ? sr : y2;
            sr = lexmin_wave_u64(sr);
            if (lane == 0) s_SR = sr;
        }
    }
    __syncthreads();

    // ---- per-step exact checks (wave 0) ----
    if (wid == 0) {
        u64 cf0 = pref[63], cf1 = pref[127];
        u64 sf1 = suf[64],  sf2 = suf[128];
        u64 PL = s_PL, SR = s_SR;
        bool ok = true;
        if (lane >= 1 && lane < NMERGE) {
            int Lp = rec_L[lane - 1], Rp = rec_R[lane - 1];
            int q1 = Lp - 2 - wlo;
            u64 ol = DEADPK;
            if (q1 >= 0) {
                ol = pref[q1];
                int r1 = q1 >> 6;
                if (r1 >= 1 && cf0 < ol) ol = cf0;
                if (r1 >= 2 && cf1 < ol) ol = cf1;
            }
            if (PL < ol) ol = PL;
            int q2 = Rp + 1 - wlo;
            u64 orr = suf[q2];
            int r2 = q2 >> 6;
            if (r2 <= 0 && sf1 < orr) orr = sf1;
            if (r2 <= 1 && sf2 < orr) orr = sf2;
            if (SR < orr) orr = SR;
            u64 O = (ol < orr) ? ol : orr;
            ok = rec_chosen[lane] < O;
        }
        if (lane == 0) ok = ok && (rec_R[NMERGE - 1] - rec_L[NMERGE - 1] == NMERGE);
        unsigned long long bad = __ballot(!ok);
        if (lane == 0) s_flag = (bad != 0ULL) ? 1 : 0;
    }
    __syncthreads();

    if (t == 0) flag_g[b] = s_flag;
    if (s_flag != 0) return;            // fallback kernel redoes this batch

    // ---- fast epilogue: write merged row + ambiguous rows directly ----
    const int Ls = rec_L[NMERGE - 1];
    if (wid == 0) {
        vfloat4 v0, v1;
        v0.x = m0r.x; v0.y = m0r.y; v0.z = m0r.z; v0.w = m0r.w;
        v1.x = m1r.x; v1.y = m1r.y; v1.z = m1r.z; v1.w = m1r.w;
        __builtin_nontemporal_store(v0, &out[((size_t)b * S_BANK + Ls) * (D / 4) + 2 * lane]);
        __builtin_nontemporal_store(v1, &out[((size_t)b * S_BANK + Ls) * (D / 4) + 2 * lane + 1]);
    }
    const int lo = (p0 - 31 > 0) ? p0 - 31 : 0;
    const int hi = (p0 < S_BANK - 1) ? p0 : S_BANK - 1;
    for (int r = lo + wid; r <= hi; r += 4) {
        if (r == Ls) continue;
        int s = (r < Ls) ? r : r + 32;
        const vfloat4* sp = (const vfloat4*)slot_gptr(s, b, bank, refresh);
        vfloat4 v0 = sp[2 * lane], v1 = sp[2 * lane + 1];
        __builtin_nontemporal_store(v0, &out[((size_t)b * S_BANK + r) * (D / 4) + 2 * lane]);
        __builtin_nontemporal_store(v1, &out[((size_t)b * S_BANK + r) * (D / 4) + 2 * lane + 1]);
    }
}

// ---------------- Kernel 3: fallback (v11 merge + full-batch gather) ---------
struct FallLds {
    unsigned short s_next[S_TOT];
    float          s_mvec[NMERGE][D];
    unsigned short s_mpos[NMERGE];
    unsigned short s_dead[NMERGE];
};

__global__ __launch_bounds__(256) void fallback_kernel(const float* __restrict__ bank,
        const float* __restrict__ refresh, const double* __restrict__ norms,
        const u64* __restrict__ c_pk_g, const int* __restrict__ flag_g,
        unsigned short* __restrict__ idx_out, vfloat4* __restrict__ out) {
    const int b = blockIdx.x;
    if (flag_g[b] == 0) return;

    __shared__ double  s_imp[S_TOT];
    __shared__ u64     c_pk[NCH];
    __shared__ FallLds G;

    const int t    = threadIdx.x;
    const int lane = t & 63;
    const int wid  = t >> 6;
    const double INF = __builtin_inf();

    if (t < NCH) c_pk[t] = c_pk_g[b * NCH + t];
    for (int j = t; j < S_TOT; j += 256) {
        s_imp[j] = norms[b * S_TOT + j];
        G.s_next[j] = (unsigned short)((j + 1 < S_TOT) ? (j + 1) : 0xFFFF);
    }
    __syncthreads();

    if (wid == 0) {
        u64 cv0 = c_pk[lane];
        u64 cv1 = c_pk[lane + 64];
        u64 cv2 = (lane == 0) ? c_pk[128] : DEADPK;

        int mpos_reg = -1;
        int prev_p = -1, prev_pv = -1, prev_nk = -1;
        int pvok = 0, nkok = 0;
        float4 mm0, mm1, pva0, pva1, pnk0, pnk1;

        for (int step = 0; step < NMERGE; ++step) {
            u64 m = (cv0 < cv1) ? cv0 : cv1;
            m = (m < cv2) ? m : cv2;
            m = lexmin_wave_u64(m);
            const int p = (int)(m & 0x3FFFULL);

            const bool hitA = pvok && (p == prev_pv);
            const bool hitB = nkok && (p == prev_p);

            int k, nk;
            float4 a0, a1, b0, b1;
            if (hitA) {
                k = prev_p; nk = prev_nk;
                a0 = pva0; a1 = pva1; b0 = mm0; b1 = mm1;
            } else if (hitB) {
                k = prev_nk; nk = G.s_next[k];
                a0 = mm0; a1 = mm1; b0 = pnk0; b1 = pnk1;
            } else {
                k = G.s_next[p]; nk = G.s_next[k];
                unsigned long long bA = __ballot((lane < step) && (mpos_reg == p));
                const int ia = bA ? (S_TOT + 63 - __clzll(bA)) : p;
                unsigned long long bB = __ballot((lane < step) && (mpos_reg == k));
                const int ib = bB ? (S_TOT + 63 - __clzll(bB)) : k;
                if (ia < S_TOT) { const float4* g = (const float4*)slot_gptr(ia, b, bank, refresh);
                                  a0 = g[2 * lane]; a1 = g[2 * lane + 1]; }
                else            { const float4* g = (const float4*)&G.s_mvec[ia - S_TOT][0];
                                  a0 = g[2 * lane]; a1 = g[2 * lane + 1]; }
                if (ib < S_TOT) { const float4* g = (const float4*)slot_gptr(ib, b, bank, refresh);
                                  b0 = g[2 * lane]; b1 = g[2 * lane + 1]; }
                else            { const float4* g = (const float4*)&G.s_mvec[ib - S_TOT][0];
                                  b0 = g[2 * lane]; b1 = g[2 * lane + 1]; }
            }

            int pv;
            if (hitB) {
                pv = prev_pv;
            } else {
                int jq = p - 1 - lane;
                bool plive = (jq >= 0) && (s_imp[jq] < 1e300);
                unsigned long long pb = __ballot(plive);
                pv = pb ? (p - __ffsll((unsigned long long)pb)) : -1;
            }

            const double imp_nk = s_imp[(nk != 0xFFFF) ? nk : 0];
            const double imp_pv = s_imp[(pv >= 0) ? pv : 0];
            const int chp = p >> 6, chk = k >> 6;
            const int chv = (pv >= 0) ? (pv >> 6) : -1;
            const int csB = (chk != chp) ? chk : -1;
            const int csC = (chv >= 0 && chv != chp && chv != chk) ? chv : -1;
            const int jjA = chp * 64 + lane;
            const bool validA = (jjA < S_TOT) && (jjA != k);
            const int rawNxtA = validA ? (int)G.s_next[jjA] : 0xFFFF;
            const double impA = validA ? s_imp[jjA] : INF;
            const int nxtA = (jjA == p) ? nk : rawNxtA;
            const double impNxtA = (nxtA != 0xFFFF) ? s_imp[nxtA] : INF;

            float4 m0, m1;
            m0.x = 0.5f * (a0.x + b0.x); m0.y = 0.5f * (a0.y + b0.y);
            m0.z = 0.5f * (a0.z + b0.z); m0.w = 0.5f * (a0.w + b0.w);
            m1.x = 0.5f * (a1.x + b1.x); m1.y = 0.5f * (a1.y + b1.y);
            m1.z = 0.5f * (a1.z + b1.z); m1.w = 0.5f * (a1.w + b1.w);
            {
                float4* dst = (float4*)&G.s_mvec[step][0];
                dst[2 * lane] = m0; dst[2 * lane + 1] = m1;
            }
            if (lane == step) mpos_reg = p;

            if (step + 1 < NMERGE) {
                prev_p = p; prev_pv = pv; prev_nk = nk;
                mm0 = m0; mm1 = m1;
                pvok = (pv >= 0); nkok = (nk != 0xFFFF);
                unsigned long long bpv = __ballot((lane <= step) && (mpos_reg == pv));
                const int ipv = bpv ? (S_TOT + 63 - __clzll(bpv)) : pv;
                unsigned long long bnk = __ballot((lane <= step) && (mpos_reg == nk));
                const int ink = bnk ? (S_TOT + 63 - __clzll(bnk)) : nk;
                if (pvok) {
                    if (ipv < S_TOT) { const float4* g = (const float4*)slot_gptr(ipv, b, bank, refresh);
                                       pva0 = g[2 * lane]; pva1 = g[2 * lane + 1]; }
                    else             { const float4* g = (const float4*)&G.s_mvec[ipv - S_TOT][0];
                                       pva0 = g[2 * lane]; pva1 = g[2 * lane + 1]; }
                }
                if (nkok) {
                    if (ink < S_TOT) { const float4* g = (const float4*)slot_gptr(ink, b, bank, refresh);
                                       pnk0 = g[2 * lane]; pnk1 = g[2 * lane + 1]; }
                    else             { const float4* g = (const float4*)&G.s_mvec[ink - S_TOT][0];
                                       pnk0 = g[2 * lane]; pnk1 = g[2 * lane + 1]; }
                }
            }

            double ss = 0.0;
            ss += (double)m0.x * m0.x + (double)m0.y * m0.y + (double)m0.z * m0.z + (double)m0.w * m0.w;
            ss += (double)m1.x * m1.x + (double)m1.y * m1.y + (double)m1.z * m1.z + (double)m1.w * m1.w;
            const double nrm = sqrt(sum_wave(ss));

            if (lane == 0) {
                G.s_next[p]    = (unsigned short)nk;
                s_imp[k]       = INF;
                s_imp[p]       = nrm;
                G.s_mpos[step] = (unsigned short)p;
                G.s_dead[step] = (unsigned short)k;
            }

            {
                u64 sc = DEADPK;
                if (validA && nxtA != 0xFFFF) {
                    double a0d = (jjA == p) ? nrm : impA;
                    if (a0d < 1e300) {
                        double a1d = (nxtA == p) ? nrm : impNxtA;
                        sc = pack_score(a0d + a1d, jjA);
                    }
                }
                sc = lexmin_wave_u64(sc);
                if (chp < 64)       { if (lane == chp)      cv0 = sc; }
                else if (chp < 128) { if (lane == chp - 64) cv1 = sc; }
                else                { if (lane == 0)        cv2 = sc; }
            }
            if (csB >= 0) {
                int jj = csB * 64 + lane;
                u64 sc = DEADPK;
                if (jj < S_TOT && jj != k) {
                    int nxt = (int)G.s_next[jj];
                    if (nxt != 0xFFFF) {
                        double a0d = s_imp[jj];
                        if (a0d < 1e300) sc = pack_score(a0d + s_imp[nxt], jj);
                    }
                }
                sc = lexmin_wave_u64(sc);
                if (csB < 64)       { if (lane == csB)      cv0 = sc; }
                else if (csB < 128) { if (lane == csB - 64) cv1 = sc; }
                else                { if (lane == 0)        cv2 = sc; }
            }
            if (csC >= 0) {
                int jj = csC * 64 + lane;
                u64 sc = DEADPK;
                if (jj < S_TOT && jj != k) {
                    int nxt = (int)G.s_next[jj];
                    if (nxt != 0xFFFF) {
                        double a0d = s_imp[jj];
                        if (a0d < 1e300) sc = pack_score(a0d + s_imp[nxt], jj);
                    }
                }
                sc = lexmin_wave_u64(sc);
                if (csC < 64)       { if (lane == csC)      cv0 = sc; }
                else if (csC < 128) { if (lane == csC - 64) cv1 = sc; }
                else                { if (lane == 0)        cv2 = sc; }
            }
        }
    }
    __syncthreads();

    // identity LUT + compacted index map (to global idx_out)
    for (int j = t; j < S_TOT; j += 256) G.s_next[j] = 0xFFFF;
    __syncthreads();
    if (t == 0)
        for (int m2 = 0; m2 < NMERGE; ++m2) G.s_next[G.s_mpos[m2]] = (unsigned short)m2;
    __syncthreads();
    for (int j = t; j < S_TOT; j += 256) {
        if (s_imp[j] < 1e300) {
            int r = j;
            #pragma unroll
            for (int m2 = 0; m2 < NMERGE; ++m2) r -= (G.s_dead[m2] < j) ? 1 : 0;
            unsigned short lut = G.s_next[j];
            idx_out[b * S_BANK + r] = (lut != 0xFFFF) ? (unsigned short)(S_TOT + lut)
                                                      : (unsigned short)j;
        }
    }
    __syncthreads();

    // full-batch gather (rare path; correctness over speed)
    for (int w = t; w < S_BANK * (D / 4); w += 256) {
        int r = w >> 7, c = w & 127;
        int src = idx_out[b * S_BANK + r];
        vfloat4 v;
        if (src < S_TOT) {
            const vfloat4* sp = (const vfloat4*)slot_gptr(src, b, bank, refresh);
            v = sp[c];
        } else {
            const vfloat4* sp = (const vfloat4*)&G.s_mvec[src - S_TOT][0];
            v = sp[c];
        }
        __builtin_nontemporal_store(v, &out[((size_t)b * S_BANK + r) * (D / 4) + c]);
    }
}

// ------------------------------------------------------------------------------
extern "C" void kernel_launch(void* const* d_in, const int* in_sizes, int n_in,
                              void* d_out, int out_size, void* d_ws, size_t ws_size,
                              hipStream_t stream) {
    const float* bank    = (const float*)d_in[0];
    const float* refresh = (const float*)d_in[1];

    double*         norms  = (double*)d_ws;
    u64*            c_pk_g = (u64*)((char*)d_ws + (size_t)B_DIM * S_TOT * sizeof(double));
    u64*            p0pk_g = (u64*)((char*)c_pk_g + (size_t)B_DIM * NCH * sizeof(u64));
    int*            flag_g = (int*)((char*)p0pk_g + B_DIM * sizeof(u64));
    unsigned short* idx    = (unsigned short*)((char*)flag_g + 64 * sizeof(int));
    vfloat4*        out    = (vfloat4*)d_out;

    hipMemsetAsync(p0pk_g, 0xFF, B_DIM * sizeof(u64), stream);   // DEADPK init
    normchunk_kernel<<<B_DIM * NCH, 256, 0, stream>>>(bank, refresh, norms, c_pk_g, p0pk_g);
    fused_kernel<<<16 + NBULK, 256, 0, stream>>>(bank, refresh, norms, c_pk_g, p0pk_g, flag_g, out);
    fallback_kernel<<<B_DIM, 256, 0, stream>>>(bank, refresh, norms, c_pk_g, flag_g, idx, out);
}

// Round 16
// 129.777 us; speedup vs baseline: 1.0921x; 1.0921x over previous
//
#include <hip/hip_runtime.h>
#include <cstdint>
#include <cstddef>

#define B_DIM  16
#define S_BANK 8192
#define S_REF  32
#define S_TOT  8224   // S_BANK + S_REF
#define NMERGE 32     // S_TOT - MAX_SLOTS
#define D      512
#define NCH    129    // ceil(S_TOT / 64)

typedef float vfloat4 __attribute__((ext_vector_type(4)));  // NT-store capable
typedef unsigned long long u64;
#define DEADPK 0xFFFFFFFFFFFFFFFFULL   // +inf sentinel in u64 ordering

// ---------------- bit helpers ------------------------------------------------
__device__ __forceinline__ int d_lo(double d){ union{double d; int i[2];}u; u.d=d; return u.i[0]; }
__device__ __forceinline__ int d_hi(double d){ union{double d; int i[2];}u; u.d=d; return u.i[1]; }
__device__ __forceinline__ double d_mk(int hi,int lo){ union{double d; int i[2];}u; u.i[0]=lo;u.i[1]=hi; return u.d; }
__device__ __forceinline__ int u_lo(u64 v){ return (int)(v & 0xFFFFFFFFULL); }
__device__ __forceinline__ int u_hi(u64 v){ return (int)(v >> 32); }
__device__ __forceinline__ u64 u_mk(int hi,int lo){ return ((u64)(unsigned)hi << 32) | (u64)(unsigned)lo; }
__device__ __forceinline__ u64 d_bits(double d){ union{double d; u64 u;}x; x.d=d; return x.u; }

// pack (positive f64 score, idx<16384) into one sortable u64 (low 14 mantissa
// bits replaced by idx => unsigned compare == lexicographic (score,idx)).
__device__ __forceinline__ u64 pack_score(double s, int j) {
    return (d_bits(s) & ~0x3FFFULL) | (u64)(unsigned)j;
}

// ---------------- DPP wave64 reductions / scans (VALU pipe) ------------------
template<int CTRL, int ROWM>
__device__ __forceinline__ u64 dpp_u64(u64 v) {
    int lo = __builtin_amdgcn_update_dpp(u_lo(v), u_lo(v), CTRL, ROWM, 0xF, false);
    int hi = __builtin_amdgcn_update_dpp(u_hi(v), u_hi(v), CTRL, ROWM, 0xF, false);
    return u_mk(hi, lo);
}
__device__ __forceinline__ u64 rl_u64(u64 v, int l) {
    int lo = __builtin_amdgcn_readlane(u_lo(v), l);
    int hi = __builtin_amdgcn_readlane(u_hi(v), l);
    return u_mk(hi, lo);
}
// reduction min over 64 lanes, broadcast
__device__ __forceinline__ u64 lexmin_wave_u64(u64 v) {
    u64 w;
    w = dpp_u64<0x111,0xF>(v); if (w < v) v = w;
    w = dpp_u64<0x112,0xF>(v); if (w < v) v = w;
    w = dpp_u64<0x114,0xF>(v); if (w < v) v = w;
    w = dpp_u64<0x118,0xF>(v); if (w < v) v = w;
    w = dpp_u64<0x142,0xF>(v); if (w < v) v = w;
    w = dpp_u64<0x143,0xF>(v); if (w < v) v = w;
    return rl_u64(v, 63);
}
// inclusive prefix-min scan (ascending lanes)
__device__ __forceinline__ u64 scan_min_incl(u64 v) {
    u64 w;
    w = dpp_u64<0x111,0xF>(v); if (w < v) v = w;   // row_shr:1
    w = dpp_u64<0x112,0xF>(v); if (w < v) v = w;
    w = dpp_u64<0x114,0xF>(v); if (w < v) v = w;
    w = dpp_u64<0x118,0xF>(v); if (w < v) v = w;
    w = dpp_u64<0x142,0xA>(v); if (w < v) v = w;   // bcast15 -> rows 1,3
    w = dpp_u64<0x143,0xC>(v); if (w < v) v = w;   // bcast31 -> rows 2,3
    return v;
}
// inclusive suffix-min scan (descending)
__device__ __forceinline__ u64 scan_min_suffix(u64 v, int lane) {
    u64 w;
    w = dpp_u64<0x101,0xF>(v); if (w < v) v = w;   // row_shl:1
    w = dpp_u64<0x102,0xF>(v); if (w < v) v = w;
    w = dpp_u64<0x104,0xF>(v); if (w < v) v = w;
    w = dpp_u64<0x108,0xF>(v); if (w < v) v = w;
    u64 t16 = rl_u64(v, 16), t32 = rl_u64(v, 32), t48 = rl_u64(v, 48);
    u64 s3 = t48;
    u64 s2 = (t32 < s3) ? t32 : s3;
    u64 s1 = (t16 < s2) ? t16 : s2;
    int row = lane >> 4;
    u64 add = (row == 0) ? s1 : (row == 1) ? s2 : (row == 2) ? s3 : DEADPK;
    if (add < v) v = add;
    return v;
}
template<int CTRL>
__device__ __forceinline__ void sum_level(double& v) {
    int lo2 = __builtin_amdgcn_update_dpp(0, d_lo(v), CTRL, 0xF, 0xF, true);
    int hi2 = __builtin_amdgcn_update_dpp(0, d_hi(v), CTRL, 0xF, 0xF, true);
    v += d_mk(hi2, lo2);
}
__device__ __forceinline__ double sum_wave(double v) {
    sum_level<0x111>(v); sum_level<0x112>(v); sum_level<0x114>(v);
    sum_level<0x118>(v); sum_level<0x142>(v); sum_level<0x143>(v);
    int lo = __builtin_amdgcn_readlane(d_lo(v), 63);
    int hi = __builtin_amdgcn_readlane(d_hi(v), 63);
    return d_mk(hi, lo);
}

// ---------------- Kernel 1: per-slot L2 norms (f64), reverse order -----------
__global__ __launch_bounds__(256) void norms_kernel(const float* __restrict__ bank,
                                                    const float* __restrict__ refresh,
                                                    double* __restrict__ norms) {
    int gw_lin = (int)((blockIdx.x * 256 + threadIdx.x) >> 6);
    int gw   = B_DIM * S_TOT - 1 - gw_lin;
    int lane = threadIdx.x & 63;
    int b = gw / S_TOT;
    int s = gw - b * S_TOT;
    const float4* src = (const float4*)(s < S_BANK
        ? bank    + ((size_t)b * S_BANK + s) * D
        : refresh + ((size_t)b * S_REF + (s - S_BANK)) * D);
    float4 f0 = src[lane];
    float4 f1 = src[lane + 64];
    double acc = 0.0;
    acc += (double)f0.x * f0.x + (double)f0.y * f0.y + (double)f0.z * f0.z + (double)f0.w * f0.w;
    acc += (double)f1.x * f1.x + (double)f1.y * f1.y + (double)f1.z * f1.z + (double)f1.w * f1.w;
    acc = sum_wave(acc);
    if (lane == 0) norms[gw] = sqrt(acc);
}

// ---------------- Kernel 1.5: packed chunk minima (parallel, whole chip) -----
__global__ __launch_bounds__(256) void chunkmin_kernel(const double* __restrict__ norms,
                                                       u64* __restrict__ c_pk_g) {
    int w    = (int)((blockIdx.x * 256 + threadIdx.x) >> 6);
    int lane = threadIdx.x & 63;
    if (w >= B_DIM * NCH) return;
    int b = w / NCH;
    int c = w - b * NCH;
    int j = c * 64 + lane;
    u64 pk = DEADPK;
    if (j <= S_TOT - 2) {
        double a = norms[b * S_TOT + j];
        double d = norms[b * S_TOT + j + 1];
        pk = pack_score(a + d, j);
    }
    pk = lexmin_wave_u64(pk);
    if (lane == 0) c_pk_g[b * NCH + c] = pk;
}

// ---------------- Kernel 2: fused walk + bulk gather -------------------------
__device__ __forceinline__ const float* slot_gptr(int id, int b,
        const float* bank, const float* refresh) {
    return (id < S_BANK) ? bank    + ((size_t)b * S_BANK + id) * D
                         : refresh + ((size_t)b * S_REF + (id - S_BANK)) * D;
}

#define NBULK (B_DIM * 4096)   // 65536 bulk blocks (2 output rows each)

__global__ __launch_bounds__(256) void fused_kernel(const float* __restrict__ bank,
        const float* __restrict__ refresh, const double* __restrict__ norms,
        const u64* __restrict__ c_pk_g, int* __restrict__ flag_g,
        vfloat4* __restrict__ out) {
    // small LDS (walk role only; keeps bulk occupancy high)
    __shared__ double s_wimp[194];     // window imps, index g - wlo
    __shared__ u64    c_pk[NCH];
    __shared__ u64    pref[192], suf[192];
    __shared__ int    rec_L[NMERGE], rec_R[NMERGE];
    __shared__ u64    rec_chosen[NMERGE];
    __shared__ u64    s_PL, s_SR;
    __shared__ int    s_flag;

    const int t    = threadIdx.x;
    const int lane = t & 63;
    const int wid  = t >> 6;
    const double INF = __builtin_inf();

    if (blockIdx.x >= 16) {
        // ================= BULK GATHER BLOCK =================
        // p0 computed redundantly per wave (no LDS, no barrier; c_pk_g is
        // L2-hot and broadcast) — bit-identical to the wave-0 argmin.
        int e  = blockIdx.x - 16;
        int b  = e >> 12;                 // 4096 blocks per batch
        int pr = (e & 4095) << 1;         // rows pr, pr+1 (same batch)
        u64 a  = (lane < NCH) ? c_pk_g[b * NCH + lane] : DEADPK;
        u64 b2 = (lane + 64 < NCH) ? c_pk_g[b * NCH + lane + 64] : DEADPK;
        u64 m = (a < b2) ? a : b2;
        u64 c2 = (lane == 0) ? c_pk_g[b * NCH + 128] : DEADPK;
        m = (m < c2) ? m : c2;
        m = lexmin_wave_u64(m);
        const int p0 = (int)(m & 0x3FFFULL);
        int r = pr + (t >> 7);
        int c = t & 127;
        // rows outside the 32-row ambiguous zone [p0-31, p0] are walk-independent
        int s = -1;
        if (r < p0 - 31)      s = r;
        else if (r > p0)      s = r + 32;
        if (s >= 0) {
            const vfloat4* sp = (const vfloat4*)slot_gptr(s, b, bank, refresh);
            vfloat4 v = sp[c];
            __builtin_nontemporal_store(v, &out[((size_t)b * S_BANK + r) * (D / 4) + c]);
        }
        return;
    }

    // ================= WALK BLOCK (b = blockIdx.x) =================
    const int b = blockIdx.x;

    if (t < NCH) c_pk[t] = c_pk_g[b * NCH + t];
    __syncthreads();

    u64 pk_min0;
    {
        u64 a = c_pk[lane];
        u64 bq = c_pk[lane + 64];
        u64 c = (lane == 0) ? c_pk[128] : DEADPK;
        u64 m = (a < bq) ? a : bq;
        m = (m < c) ? m : c;
        pk_min0 = lexmin_wave_u64(m);
    }
    const int p0 = (int)(pk_min0 & 0x3FFFULL);

    const int cmid = p0 >> 6;
    int wsx = cmid - 1;
    if (wsx < 0) wsx = 0;
    if (wsx > NCH - 3) wsx = NCH - 3;
    const int ws  = wsx;
    const int wlo = ws * 64;

    // stage ONLY the window imps (194 doubles)
    for (int j = t; j < 194; j += 256) {
        int g = wlo + j;
        if (g < S_TOT) s_wimp[j] = norms[b * S_TOT + g];
    }
    __syncthreads();

    float4 m0r, m1r;           // final merged vector (wave 0)

    if (wid == 0) {
        // ---- wave 0: cascade walk with register prefetch pipeline ----
        const float4* gA = (const float4*)slot_gptr(p0, b, bank, refresh);
        const float4* gB = (const float4*)slot_gptr(p0 + 1, b, bank, refresh);
        float4 a0 = gA[2 * lane], a1 = gA[2 * lane + 1];
        float4 b0 = gB[2 * lane], b1 = gB[2 * lane + 1];
        int q;
        q = (p0 - 1 >= 0) ? p0 - 1 : 0;
        const float4* gq = (const float4*)slot_gptr(q, b, bank, refresh);
        float4 cL0 = gq[2 * lane], cL1 = gq[2 * lane + 1];
        q = (p0 + 2 <= S_TOT - 1) ? p0 + 2 : S_TOT - 1;
        gq = (const float4*)slot_gptr(q, b, bank, refresh);
        float4 cR0 = gq[2 * lane], cR1 = gq[2 * lane + 1];
        q = (p0 - 2 >= 0) ? p0 - 2 : 0;
        gq = (const float4*)slot_gptr(q, b, bank, refresh);
        float4 fL0 = gq[2 * lane], fL1 = gq[2 * lane + 1];
        q = (p0 + 3 <= S_TOT - 1) ? p0 + 3 : S_TOT - 1;
        gq = (const float4*)slot_gptr(q, b, bank, refresh);
        float4 fR0 = gq[2 * lane], fR1 = gq[2 * lane + 1];

        m0r.x = 0.5f * (a0.x + b0.x); m0r.y = 0.5f * (a0.y + b0.y);
        m0r.z = 0.5f * (a0.z + b0.z); m0r.w = 0.5f * (a0.w + b0.w);
        m1r.x = 0.5f * (a1.x + b1.x); m1r.y = 0.5f * (a1.y + b1.y);
        m1r.z = 0.5f * (a1.z + b1.z); m1r.w = 0.5f * (a1.w + b1.w);
        double ss = 0.0;
        ss += (double)m0r.x * m0r.x + (double)m0r.y * m0r.y + (double)m0r.z * m0r.z + (double)m0r.w * m0r.w;
        ss += (double)m1r.x * m1r.x + (double)m1r.y * m1r.y + (double)m1r.z * m1r.z + (double)m1r.w * m1r.w;
        double nrm = sqrt(sum_wave(ss));
        int L = p0, R = p0 + 1;
        if (t == 0) { rec_L[0] = L; rec_R[0] = R; rec_chosen[0] = pk_min0; }

        for (int step = 1; step < NMERGE; ++step) {
            const int cl = L - 1, cr = R + 1;
            const bool hasL = (cl >= 0);
            const bool hasR = (cr < S_TOT);
            const double il = hasL ? s_wimp[cl - wlo] : INF;
            const double ir = hasR ? s_wimp[cr - wlo] : INF;
            const u64 pkL = hasL ? pack_score(il + nrm, cl) : DEADPK;
            const u64 pkR = hasR ? pack_score(nrm + ir, L)  : DEADPK;
            const bool goL = (pkL < pkR);
            const u64 chosen = goL ? pkL : pkR;
            float4 a0s, a1s, b0s, b1s;
            if (goL) { a0s = cL0; a1s = cL1; b0s = m0r; b1s = m1r; }
            else     { a0s = m0r; a1s = m1r; b0s = cR0; b1s = cR1; }
            m0r.x = 0.5f * (a0s.x + b0s.x); m0r.y = 0.5f * (a0s.y + b0s.y);
            m0r.z = 0.5f * (a0s.z + b0s.z); m0r.w = 0.5f * (a0s.w + b0s.w);
            m1r.x = 0.5f * (a1s.x + b1s.x); m1r.y = 0.5f * (a1s.y + b1s.y);
            m1r.z = 0.5f * (a1s.z + b1s.z); m1r.w = 0.5f * (a1s.w + b1s.w);
            if (goL) {
                L = cl;
                cL0 = fL0; cL1 = fL1;
                int nq = (L - 2 >= 0) ? L - 2 : 0;
                const float4* gp = (const float4*)slot_gptr(nq, b, bank, refresh);
                fL0 = gp[2 * lane]; fL1 = gp[2 * lane + 1];
            } else {
                R = cr;
                cR0 = fR0; cR1 = fR1;
                int nq = (R + 2 <= S_TOT - 1) ? R + 2 : S_TOT - 1;
                const float4* gp = (const float4*)slot_gptr(nq, b, bank, refresh);
                fR0 = gp[2 * lane]; fR1 = gp[2 * lane + 1];
            }
            double ss2 = 0.0;
            ss2 += (double)m0r.x * m0r.x + (double)m0r.y * m0r.y + (double)m0r.z * m0r.z + (double)m0r.w * m0r.w;
            ss2 += (double)m1r.x * m1r.x + (double)m1r.y * m1r.y + (double)m1r.z * m1r.z + (double)m1r.w * m1r.w;
            nrm = sqrt(sum_wave(ss2));
            if (t == 0) { rec_L[step] = L; rec_R[step] = R; rec_chosen[step] = chosen; }
        }
    } else {
        // ---- waves 1-3: validation precompute, CONCURRENT with walk ----
        int c = ws + (wid - 1);
        int idx = c * 64 + lane;
        u64 pk0 = (idx <= S_TOT - 2)
                    ? pack_score(s_wimp[idx - wlo] + s_wimp[idx + 1 - wlo], idx)
                    : DEADPK;
        pref[idx - wlo] = scan_min_incl(pk0);
        suf[idx - wlo]  = scan_min_suffix(pk0, lane);
        if (wid == 1) {
            u64 x0 = (lane < ws) ? c_pk[lane] : DEADPK;
            u64 x1 = (lane + 64 < ws) ? c_pk[lane + 64] : DEADPK;
            u64 pl = (x0 < x1) ? x0 : x1;
            pl = lexmin_wave_u64(pl);
            if (lane == 0) s_PL = pl;
        }
        if (wid == 2) {
            u64 y0 = (lane > ws + 2) ? c_pk[lane] : DEADPK;
            u64 y1 = (lane + 64 > ws + 2) ? c_pk[lane + 64] : DEADPK;
            u64 y2 = (lane == 0 && 128 > ws + 2) ? c_pk[128] : DEADPK;
            u64 sr = (y0 < y1) ? y0 : y1;
            sr = (sr < y2) ? sr : y2;
            sr = lexmin_wave_u64(sr);
            if (lane == 0) s_SR = sr;
        }
    }
    __syncthreads();

    // ---- per-step exact checks (wave 0) ----
    if (wid == 0) {
        u64 cf0 = pref[63], cf1 = pref[127];
        u64 sf1 = suf[64],  sf2 = suf[128];
        u64 PL = s_PL, SR = s_SR;
        bool ok = true;
        if (lane >= 1 && lane < NMERGE) {
            int Lp = rec_L[lane - 1], Rp = rec_R[lane - 1];
            int q1 = Lp - 2 - wlo;
            u64 ol = DEADPK;
            if (q1 >= 0) {
                ol = pref[q1];
                int r1 = q1 >> 6;
                if (r1 >= 1 && cf0 < ol) ol = cf0;
                if (r1 >= 2 && cf1 < ol) ol = cf1;
            }
            if (PL < ol) ol = PL;
            int q2 = Rp + 1 - wlo;
            u64 orr = suf[q2];
            int r2 = q2 >> 6;
            if (r2 <= 0 && sf1 < orr) orr = sf1;
            if (r2 <= 1 && sf2 < orr) orr = sf2;
            if (SR < orr) orr = SR;
            u64 O = (ol < orr) ? ol : orr;
            ok = rec_chosen[lane] < O;
        }
        if (lane == 0) ok = ok && (rec_R[NMERGE - 1] - rec_L[NMERGE - 1] == NMERGE);
        unsigned long long bad = __ballot(!ok);
        if (lane == 0) s_flag = (bad != 0ULL) ? 1 : 0;
    }
    __syncthreads();

    if (t == 0) flag_g[b] = s_flag;
    if (s_flag != 0) return;            // fallback kernel redoes this batch

    // ---- fast epilogue: write merged row + ambiguous rows directly ----
    const int Ls = rec_L[NMERGE - 1];
    if (wid == 0) {
        vfloat4 v0, v1;
        v0.x = m0r.x; v0.y = m0r.y; v0.z = m0r.z; v0.w = m0r.w;
        v1.x = m1r.x; v1.y = m1r.y; v1.z = m1r.z; v1.w = m1r.w;
        __builtin_nontemporal_store(v0, &out[((size_t)b * S_BANK + Ls) * (D / 4) + 2 * lane]);
        __builtin_nontemporal_store(v1, &out[((size_t)b * S_BANK + Ls) * (D / 4) + 2 * lane + 1]);
    }
    const int lo = (p0 - 31 > 0) ? p0 - 31 : 0;
    const int hi = (p0 < S_BANK - 1) ? p0 : S_BANK - 1;
    for (int r = lo + wid; r <= hi; r += 4) {
        if (r == Ls) continue;
        int s = (r < Ls) ? r : r + 32;
        const vfloat4* sp = (const vfloat4*)slot_gptr(s, b, bank, refresh);
        vfloat4 v0 = sp[2 * lane], v1 = sp[2 * lane + 1];
        __builtin_nontemporal_store(v0, &out[((size_t)b * S_BANK + r) * (D / 4) + 2 * lane]);
        __builtin_nontemporal_store(v1, &out[((size_t)b * S_BANK + r) * (D / 4) + 2 * lane + 1]);
    }
}

// ---------------- Kernel 3: fallback (v11 merge + full-batch gather) ---------
struct FallLds {
    unsigned short s_next[S_TOT];
    float          s_mvec[NMERGE][D];
    unsigned short s_mpos[NMERGE];
    unsigned short s_dead[NMERGE];
};

__global__ __launch_bounds__(256) void fallback_kernel(const float* __restrict__ bank,
        const float* __restrict__ refresh, const double* __restrict__ norms,
        const u64* __restrict__ c_pk_g, const int* __restrict__ flag_g,
        unsigned short* __restrict__ idx_out, vfloat4* __restrict__ out) {
    const int b = blockIdx.x;
    if (flag_g[b] == 0) return;

    __shared__ double  s_imp[S_TOT];
    __shared__ u64     c_pk[NCH];
    __shared__ FallLds G;

    const int t    = threadIdx.x;
    const int lane = t & 63;
    const int wid  = t >> 6;
    const double INF = __builtin_inf();

    if (t < NCH) c_pk[t] = c_pk_g[b * NCH + t];
    for (int j = t; j < S_TOT; j += 256) {
        s_imp[j] = norms[b * S_TOT + j];
        G.s_next[j] = (unsigned short)((j + 1 < S_TOT) ? (j + 1) : 0xFFFF);
    }
    __syncthreads();

    if (wid == 0) {
        u64 cv0 = c_pk[lane];
        u64 cv1 = c_pk[lane + 64];
        u64 cv2 = (lane == 0) ? c_pk[128] : DEADPK;

        int mpos_reg = -1;
        int prev_p = -1, prev_pv = -1, prev_nk = -1;
        int pvok = 0, nkok = 0;
        float4 mm0, mm1, pva0, pva1, pnk0, pnk1;

        for (int step = 0; step < NMERGE; ++step) {
            u64 m = (cv0 < cv1) ? cv0 : cv1;
            m = (m < cv2) ? m : cv2;
            m = lexmin_wave_u64(m);
            const int p = (int)(m & 0x3FFFULL);

            const bool hitA = pvok && (p == prev_pv);
            const bool hitB = nkok && (p == prev_p);

            int k, nk;
            float4 a0, a1, b0, b1;
            if (hitA) {
                k = prev_p; nk = prev_nk;
                a0 = pva0; a1 = pva1; b0 = mm0; b1 = mm1;
            } else if (hitB) {
                k = prev_nk; nk = G.s_next[k];
                a0 = mm0; a1 = mm1; b0 = pnk0; b1 = pnk1;
            } else {
                k = G.s_next[p]; nk = G.s_next[k];
                unsigned long long bA = __ballot((lane < step) && (mpos_reg == p));
                const int ia = bA ? (S_TOT + 63 - __clzll(bA)) : p;
                unsigned long long bB = __ballot((lane < step) && (mpos_reg == k));
                const int ib = bB ? (S_TOT + 63 - __clzll(bB)) : k;
                if (ia < S_TOT) { const float4* g = (const float4*)slot_gptr(ia, b, bank, refresh);
                                  a0 = g[2 * lane]; a1 = g[2 * lane + 1]; }
                else            { const float4* g = (const float4*)&G.s_mvec[ia - S_TOT][0];
                                  a0 = g[2 * lane]; a1 = g[2 * lane + 1]; }
                if (ib < S_TOT) { const float4* g = (const float4*)slot_gptr(ib, b, bank, refresh);
                                  b0 = g[2 * lane]; b1 = g[2 * lane + 1]; }
                else            { const float4* g = (const float4*)&G.s_mvec[ib - S_TOT][0];
                                  b0 = g[2 * lane]; b1 = g[2 * lane + 1]; }
            }

            int pv;
            if (hitB) {
                pv = prev_pv;
            } else {
                int jq = p - 1 - lane;
                bool plive = (jq >= 0) && (s_imp[jq] < 1e300);
                unsigned long long pb = __ballot(plive);
                pv = pb ? (p - __ffsll((unsigned long long)pb)) : -1;
            }

            const double imp_nk = s_imp[(nk != 0xFFFF) ? nk : 0];
            const double imp_pv = s_imp[(pv >= 0) ? pv : 0];
            const int chp = p >> 6, chk = k >> 6;
            const int chv = (pv >= 0) ? (pv >> 6) : -1;
            const int csB = (chk != chp) ? chk : -1;
            const int csC = (chv >= 0 && chv != chp && chv != chk) ? chv : -1;
            const int jjA = chp * 64 + lane;
            const bool validA = (jjA < S_TOT) && (jjA != k);
            const int rawNxtA = validA ? (int)G.s_next[jjA] : 0xFFFF;
            const double impA = validA ? s_imp[jjA] : INF;
            const int nxtA = (jjA == p) ? nk : rawNxtA;
            const double impNxtA = (nxtA != 0xFFFF) ? s_imp[nxtA] : INF;

            float4 m0, m1;
            m0.x = 0.5f * (a0.x + b0.x); m0.y = 0.5f * (a0.y + b0.y);
            m0.z = 0.5f * (a0.z + b0.z); m0.w = 0.5f * (a0.w + b0.w);
            m1.x = 0.5f * (a1.x + b1.x); m1.y = 0.5f * (a1.y + b1.y);
            m1.z = 0.5f * (a1.z + b1.z); m1.w = 0.5f * (a1.w + b1.w);
            {
                float4* dst = (float4*)&G.s_mvec[step][0];
                dst[2 * lane] = m0; dst[2 * lane + 1] = m1;
            }
            if (lane == step) mpos_reg = p;

            if (step + 1 < NMERGE) {
                prev_p = p; prev_pv = pv; prev_nk = nk;
                mm0 = m0; mm1 = m1;
                pvok = (pv >= 0); nkok = (nk != 0xFFFF);
                unsigned long long bpv = __ballot((lane <= step) && (mpos_reg == pv));
                const int ipv = bpv ? (S_TOT + 63 - __clzll(bpv)) : pv;
                unsigned long long bnk = __ballot((lane <= step) && (mpos_reg == nk));
                const int ink = bnk ? (S_TOT + 63 - __clzll(bnk)) : nk;
                if (pvok) {
                    if (ipv < S_TOT) { const float4* g = (const float4*)slot_gptr(ipv, b, bank, refresh);
                                       pva0 = g[2 * lane]; pva1 = g[2 * lane + 1]; }
                    else             { const float4* g = (const float4*)&G.s_mvec[ipv - S_TOT][0];
                                       pva0 = g[2 * lane]; pva1 = g[2 * lane + 1]; }
                }
                if (nkok) {
                    if (ink < S_TOT) { const float4* g = (const float4*)slot_gptr(ink, b, bank, refresh);
                                       pnk0 = g[2 * lane]; pnk1 = g[2 * lane + 1]; }
                    else             { const float4* g = (const float4*)&G.s_mvec[ink - S_TOT][0];
                                       pnk0 = g[2 * lane]; pnk1 = g[2 * lane + 1]; }
                }
            }

            double ss = 0.0;
            ss += (double)m0.x * m0.x + (double)m0.y * m0.y + (double)m0.z * m0.z + (double)m0.w * m0.w;
            ss += (double)m1.x * m1.x + (double)m1.y * m1.y + (double)m1.z * m1.z + (double)m1.w * m1.w;
            const double nrm = sqrt(sum_wave(ss));

            if (lane == 0) {
                G.s_next[p]    = (unsigned short)nk;
                s_imp[k]       = INF;
                s_imp[p]       = nrm;
                G.s_mpos[step] = (unsigned short)p;
                G.s_dead[step] = (unsigned short)k;
            }

            {
                u64 sc = DEADPK;
                if (validA && nxtA != 0xFFFF) {
                    double a0d = (jjA == p) ? nrm : impA;
                    if (a0d < 1e300) {
                        double a1d = (nxtA == p) ? nrm : impNxtA;
                        sc = pack_score(a0d + a1d, jjA);
                    }
                }
                sc = lexmin_wave_u64(sc);
                if (chp < 64)       { if (lane == chp)      cv0 = sc; }
                else if (chp < 128) { if (lane == chp - 64) cv1 = sc; }
                else                { if (lane == 0)        cv2 = sc; }
            }
            if (csB >= 0) {
                int jj = csB * 64 + lane;
                u64 sc = DEADPK;
                if (jj < S_TOT && jj != k) {
                    int nxt = (int)G.s_next[jj];
                    if (nxt != 0xFFFF) {
                        double a0d = s_imp[jj];
                        if (a0d < 1e300) sc = pack_score(a0d + s_imp[nxt], jj);
                    }
                }
                sc = lexmin_wave_u64(sc);
                if (csB < 64)       { if (lane == csB)      cv0 = sc; }
                else if (csB < 128) { if (lane == csB - 64) cv1 = sc; }
                else                { if (lane == 0)        cv2 = sc; }
            }
            if (csC >= 0) {
                int jj = csC * 64 + lane;
                u64 sc = DEADPK;
                if (jj < S_TOT && jj != k) {
                    int nxt = (int)G.s_next[jj];
                    if (nxt != 0xFFFF) {
                        double a0d = s_imp[jj];
                        if (a0d < 1e300) sc = pack_score(a0d + s_imp[nxt], jj);
                    }
                }
                sc = lexmin_wave_u64(sc);
                if (csC < 64)       { if (lane == csC)      cv0 = sc; }
                else if (csC < 128) { if (lane == csC - 64) cv1 = sc; }
                else                { if (lane == 0)        cv2 = sc; }
            }
        }
    }
    __syncthreads();

    // identity LUT + compacted index map (to global idx_out)
    for (int j = t; j < S_TOT; j += 256) G.s_next[j] = 0xFFFF;
    __syncthreads();
    if (t == 0)
        for (int m2 = 0; m2 < NMERGE; ++m2) G.s_next[G.s_mpos[m2]] = (unsigned short)m2;
    __syncthreads();
    for (int j = t; j < S_TOT; j += 256) {
        if (s_imp[j] < 1e300) {
            int r = j;
            #pragma unroll
            for (int m2 = 0; m2 < NMERGE; ++m2) r -= (G.s_dead[m2] < j) ? 1 : 0;
            unsigned short lut = G.s_next[j];
            idx_out[b * S_BANK + r] = (lut != 0xFFFF) ? (unsigned short)(S_TOT + lut)
                                                      : (unsigned short)j;
        }
    }
    __syncthreads();

    // full-batch gather (rare path; correctness over speed)
    for (int w = t; w < S_BANK * (D / 4); w += 256) {
        int r = w >> 7, c = w & 127;
        int src = idx_out[b * S_BANK + r];
        vfloat4 v;
        if (src < S_TOT) {
            const vfloat4* sp = (const vfloat4*)slot_gptr(src, b, bank, refresh);
            v = sp[c];
        } else {
            const vfloat4* sp = (const vfloat4*)&G.s_mvec[src - S_TOT][0];
            v = sp[c];
        }
        __builtin_nontemporal_store(v, &out[((size_t)b * S_BANK + r) * (D / 4) + c]);
    }
}

// ------------------------------------------------------------------------------
extern "C" void kernel_launch(void* const* d_in, const int* in_sizes, int n_in,
                              void* d_out, int out_size, void* d_ws, size_t ws_size,
                              hipStream_t stream) {
    const float* bank    = (const float*)d_in[0];
    const float* refresh = (const float*)d_in[1];

    double*         norms  = (double*)d_ws;
    u64*            c_pk_g = (u64*)((char*)d_ws + (size_t)B_DIM * S_TOT * sizeof(double));
    int*            flag_g = (int*)((char*)c_pk_g + (size_t)B_DIM * NCH * sizeof(u64));
    unsigned short* idx    = (unsigned short*)((char*)flag_g + 64 * sizeof(int));
    vfloat4*        out    = (vfloat4*)d_out;

    norms_kernel<<<(B_DIM * S_TOT) / 4, 256, 0, stream>>>(bank, refresh, norms);
    chunkmin_kernel<<<(B_DIM * NCH * 64 + 255) / 256, 256, 0, stream>>>(norms, c_pk_g);
    fused_kernel<<<16 + NBULK, 256, 0, stream>>>(bank, refresh, norms, c_pk_g, flag_g, out);
    fallback_kernel<<<B_DIM, 256, 0, stream>>>(bank, refresh, norms, c_pk_g, flag_g, idx, out);
}